// Round 12
// baseline (418.847 us; speedup 1.0000x reference)
//
#include <hip/hip_runtime.h>

// WaveGC wavelet conv. Round 12 = R11 with the filter re-tiled 128x64 -> 128x128
// (4 waves of 64x64, m97-proven shape). R11 post-mortem: filter was LDS-port
// bound (B-frag reads duplicated across 4 waves; staging+reads ~560 cyc vs
// 233 MFMA per k-step -> 41% cap, measured 31-35%). 128x128 doubles MFMA per
// byte through the port (cap ~62%) and halves staged bytes per output.
// Triangular pairs now 136/t (diag tiles skip B staging; B == A tile).
// Persistent 512-block grid (2 blocks/CU @ 64 KB LDS).
//
//  filter: F_t = A_t A_t^T (fp32) + fused row/col sumsq, triangular tiles
//  st1   : PT  = NT(WgT_pad, x)
//  st4   : HT  = relu(NT(PT, G) + bg)    G = mask+scale staged from F fp32
//  st5   : combT = NT(HT, G) stored transposed
//  st6   : out = relu(NT(comb, WfT) + bf)
//
// ws (fused):   F fp32 [4][N][N] @0 (67.1M) | A4 @67.1M (67.1M) | tail @134.2M
// ws (fallback):F fp32 @0 | A1 @67.1M (16.8M) | tail @83.9M

#define NN 2048
#define NPW 4194304L   // N*N

typedef short bf16x8 __attribute__((ext_vector_type(8)));
typedef float f32x4  __attribute__((ext_vector_type(4)));

__device__ inline unsigned short bf16_rne(float f) {
    unsigned int u = __float_as_uint(f);
    u += 0x7fffu + ((u >> 16) & 1u);
    return (unsigned short)(u >> 16);
}
__device__ inline float bf16_f(unsigned short h) {
    return __uint_as_float((unsigned)h << 16);
}

__device__ inline void load_lds16(const void* g, void* l) {
    __builtin_amdgcn_global_load_lds(
        (const __attribute__((address_space(1))) unsigned int*)(unsigned long)g,
        (__attribute__((address_space(3))) unsigned int*)(unsigned long)l,
        16, 0, 0);
}

// masked+scaled+split 8-element chunk -> packed hi/lo uint4
__device__ inline void gmask_chunk(const float* src, float iv,
                                   uint4* hi, uint4* lo)
{
    float4 v0 = *(const float4*)src;
    float4 v1 = *(const float4*)(src + 4);
    float a[8] = {v0.x, v0.y, v0.z, v0.w, v1.x, v1.y, v1.z, v1.w};
    unsigned int hw[4], lw[4];
    #pragma unroll
    for (int d = 0; d < 4; ++d) {
        unsigned int hword = 0, lword = 0;
        #pragma unroll
        for (int e = 0; e < 2; ++e) {
            float g = a[d * 2 + e] * iv;
            g = (fabsf(g) > 1e-4f) ? g : 0.f;
            unsigned short h = bf16_rne(g);
            unsigned short l = bf16_rne(g - bf16_f(h));
            hword |= (unsigned int)h << (16 * e);
            lword |= (unsigned int)l << (16 * e);
        }
        hw[d] = hword; lw[d] = lword;
    }
    *hi = *(uint4*)hw; *lo = *(uint4*)lw;
}

// ---------------------------------------------------------------------------
// Persistent triangular filter: F = A A^T fp32 + fused row/col sumsq.
// 128x128 tile, BK=64, 4 waves of 64x64 quadrants, DMA staging.
// Tile list: t = idx/136, pair = idx%136 -> (it<=jt) over 16x16 blocks.
// Diagonal pairs (it==jt): B tile == A tile (skip B staging). Mirror writes
// + mirror col-sumsq for jt>it.
// ---------------------------------------------------------------------------
__global__ __launch_bounds__(256, 2)
void filter_persist(const unsigned short* __restrict__ AhB,
                    const unsigned short* __restrict__ AlB,
                    float* __restrict__ FB, float* __restrict__ ssB,
                    long sA, int ntiles, unsigned* __restrict__ ctr)
{
    __shared__ unsigned short sAh[128 * 64];
    __shared__ unsigned short sAl[128 * 64];
    __shared__ unsigned short sBh[128 * 64];
    __shared__ unsigned short sBl[128 * 64];
    __shared__ int s_idx;

    const int K = NN, N = NN;
    int tid = threadIdx.x;
    int lane = tid & 63, w = tid >> 6;
    int wbase = w * 64;
    int wr = (w & 1) * 64, wc = (w >> 1) * 64;
    int q = lane >> 4, r15 = lane & 15;

    for (;;) {
        if (tid == 0) s_idx = (int)atomicAdd(ctr, 1u);
        __syncthreads();
        int idx = s_idx;
        if (idx >= ntiles) return;

        int z = idx / 136;
        int rem = idx - z * 136;
        int it = 0, span = 16;
        while (rem >= span) { rem -= span; ++it; --span; }
        int jt = it + rem;
        int i0 = it * 128, j0 = jt * 128;
        bool diag = (it == jt);

        const unsigned short* Ah = AhB + z * sA;
        const unsigned short* Al = AlB + z * sA;
        float* F = FB + (long)z * NPW;
        float* sumsq = ssB + z * NN;

        f32x4 acc[4][4];
        #pragma unroll
        for (int i = 0; i < 4; ++i)
            #pragma unroll
            for (int j = 0; j < 4; ++j)
                acc[i][j] = (f32x4){0.f, 0.f, 0.f, 0.f};

        for (int k0 = 0; k0 < K; k0 += 64) {
            #pragma unroll
            for (int p = 0; p < 4; ++p) {
                int c = p * 256 + wbase + lane;
                int row = c >> 3;
                int gsw = (c & 7) ^ (row & 7);
                long off = (long)(i0 + row) * K + k0 + gsw * 8;
                int ldst = (p * 256 + wbase) * 8;
                load_lds16(Ah + off, &sAh[ldst]);
                load_lds16(Al + off, &sAl[ldst]);
            }
            if (!diag) {
                #pragma unroll
                for (int p = 0; p < 4; ++p) {
                    int c = p * 256 + wbase + lane;
                    int row = c >> 3;
                    int gsw = (c & 7) ^ (row & 7);
                    long off = (long)(j0 + row) * K + k0 + gsw * 8;
                    int ldst = (p * 256 + wbase) * 8;
                    load_lds16(Ah + off, &sBh[ldst]);
                    load_lds16(Al + off, &sBl[ldst]);
                }
            }
            __syncthreads();

            const unsigned short* bh = diag ? sAh : sBh;
            const unsigned short* bl = diag ? sAl : sBl;

            #pragma unroll
            for (int s = 0; s < 2; ++s) {
                int g = s * 4 + q;
                bf16x8 fAh[4], fAl[4], fBh[4], fBl[4];
                #pragma unroll
                for (int f = 0; f < 4; ++f) {
                    int ra = wr + f * 16 + r15;
                    int aa = ra * 64 + ((g ^ (ra & 7)) * 8);
                    fAh[f] = *(const bf16x8*)&sAh[aa];
                    fAl[f] = *(const bf16x8*)&sAl[aa];
                    int rb = wc + f * 16 + r15;
                    int ab = rb * 64 + ((g ^ (rb & 7)) * 8);
                    fBh[f] = *(const bf16x8*)&bh[ab];
                    fBl[f] = *(const bf16x8*)&bl[ab];
                }
                #pragma unroll
                for (int fi = 0; fi < 4; ++fi)
                    #pragma unroll
                    for (int fj = 0; fj < 4; ++fj) {
                        acc[fi][fj] = __builtin_amdgcn_mfma_f32_16x16x32_bf16(
                            fAh[fi], fBh[fj], acc[fi][fj], 0, 0, 0);
                        acc[fi][fj] = __builtin_amdgcn_mfma_f32_16x16x32_bf16(
                            fAh[fi], fBl[fj], acc[fi][fj], 0, 0, 0);
                        acc[fi][fj] = __builtin_amdgcn_mfma_f32_16x16x32_bf16(
                            fAl[fi], fBh[fj], acc[fi][fj], 0, 0, 0);
                    }
            }
            __syncthreads();
        }

        // row-sumsq (direct contribution; two waves share rows -> atomics ok)
        #pragma unroll
        for (int fi = 0; fi < 4; ++fi)
            #pragma unroll
            for (int r = 0; r < 4; ++r) {
                float s = 0.f;
                #pragma unroll
                for (int fj = 0; fj < 4; ++fj) {
                    float v = acc[fi][fj][r];
                    s += v * v;
                }
                s += __shfl_xor(s, 1); s += __shfl_xor(s, 2);
                s += __shfl_xor(s, 4); s += __shfl_xor(s, 8);
                if (r15 == 0)
                    atomicAdd(&sumsq[i0 + wr + fi * 16 + q * 4 + r], s);
            }

        bool mirror = !diag;
        if (mirror) {
            #pragma unroll
            for (int fj = 0; fj < 4; ++fj) {
                float s = 0.f;
                #pragma unroll
                for (int fi = 0; fi < 4; ++fi)
                    #pragma unroll
                    for (int r = 0; r < 4; ++r) {
                        float v = acc[fi][fj][r];
                        s += v * v;
                    }
                s += __shfl_xor(s, 16); s += __shfl_xor(s, 32);
                if (lane < 16)
                    atomicAdd(&sumsq[j0 + wc + fj * 16 + lane], s);
            }
        }

        #pragma unroll
        for (int fi = 0; fi < 4; ++fi)
            #pragma unroll
            for (int fj = 0; fj < 4; ++fj) {
                int col = j0 + wc + fj * 16 + r15;
                #pragma unroll
                for (int r = 0; r < 4; ++r) {
                    int row = i0 + wr + fi * 16 + q * 4 + r;
                    float v = acc[fi][fj][r];
                    F[(long)row * N + col] = v;
                    if (mirror) F[(long)col * N + row] = v;
                }
            }
    }
}

// ---------------------------------------------------------------------------
// Generic NT GEMM (R9/R11 proven body, unchanged). A side: DMA staged.
// B side: DMA, or GB: gmask-staged from fp32 F. BIASM: 0/1/2. TSTORE: st5.
// ---------------------------------------------------------------------------
template<int BIASM, bool RELU, bool OUTF32, bool GB, bool TSTORE>
__global__ __launch_bounds__(256, 3)
void nt_gemm(const unsigned short* __restrict__ Ah, const unsigned short* __restrict__ Al,
             const unsigned short* __restrict__ Bh, const unsigned short* __restrict__ Bl,
             const float* __restrict__ Bf,
             unsigned short* __restrict__ Ch, unsigned short* __restrict__ Cl,
             float* __restrict__ Cf,
             const float* __restrict__ bias, const float* __restrict__ rowss,
             int K, int a_rows, int b_rows, int i_valid, int j_valid, int ldc,
             long sA, long sB, long sC, int sBias)
{
    __shared__ unsigned short sAh[128 * 64];
    __shared__ unsigned short sAl[128 * 64];
    __shared__ unsigned short sBh[64 * 64];
    __shared__ unsigned short sBl[64 * 64];

    int z = blockIdx.z;
    Ah += z * sA; Al += z * sA;
    if (GB) Bf += z * sB; else { Bh += z * sB; Bl += z * sB; }
    if (OUTF32) Cf += z * sC; else { Ch += z * sC; Cl += z * sC; }
    if (BIASM)  bias += (long)z * sBias;
    if (GB) rowss += z * NN;

    int i0 = blockIdx.y * 128, j0 = blockIdx.x * 64;
    int tid = threadIdx.x;
    int lane = tid & 63, w = tid >> 6;
    int wbase = w * 64;
    int wr = w * 32;
    int q = lane >> 4, r15 = lane & 15;

    f32x4 acc[2][4];
    #pragma unroll
    for (int i = 0; i < 2; ++i)
        #pragma unroll
        for (int j = 0; j < 4; ++j)
            acc[i][j] = (f32x4){0.f, 0.f, 0.f, 0.f};

    for (int k0 = 0; k0 < K; k0 += 64) {
        #pragma unroll
        for (int p = 0; p < 4; ++p) {
            int c = p * 256 + wbase + lane;
            int row = c >> 3;
            int gsw = (c & 7) ^ (row & 7);
            int ra = min(i0 + row, a_rows - 1);
            long off = (long)ra * K + k0 + gsw * 8;
            int ldst = (p * 256 + wbase) * 8;
            load_lds16(Ah + off, &sAh[ldst]);
            load_lds16(Al + off, &sAl[ldst]);
        }
        if (GB) {
            #pragma unroll
            for (int p = 0; p < 2; ++p) {
                int c = p * 256 + tid;
                int row = c >> 3, g = c & 7;
                int rb = min(j0 + row, b_rows - 1);
                float iv = 1.f / fmaxf(sqrtf(rowss[rb]), 1e-12f);
                uint4 hi, lo;
                gmask_chunk(Bf + (long)rb * K + k0 + g * 8, iv, &hi, &lo);
                int slot = row * 64 + ((g ^ (row & 7)) * 8);
                *(uint4*)&sBh[slot] = hi;
                *(uint4*)&sBl[slot] = lo;
            }
        } else {
            #pragma unroll
            for (int p = 0; p < 2; ++p) {
                int c = p * 256 + wbase + lane;
                int row = c >> 3;
                int gsw = (c & 7) ^ (row & 7);
                int rb = min(j0 + row, b_rows - 1);
                long off = (long)rb * K + k0 + gsw * 8;
                int ldst = (p * 256 + wbase) * 8;
                load_lds16(Bh + off, &sBh[ldst]);
                load_lds16(Bl + off, &sBl[ldst]);
            }
        }
        __syncthreads();

        #pragma unroll
        for (int s = 0; s < 2; ++s) {
            int g = s * 4 + q;
            bf16x8 fAh[2], fAl[2], fBh[4], fBl[4];
            #pragma unroll
            for (int f = 0; f < 2; ++f) {
                int ra = wr + f * 16 + r15;
                int aa = ra * 64 + ((g ^ (ra & 7)) * 8);
                fAh[f] = *(const bf16x8*)&sAh[aa];
                fAl[f] = *(const bf16x8*)&sAl[aa];
            }
            #pragma unroll
            for (int f = 0; f < 4; ++f) {
                int rb = f * 16 + r15;
                int ab = rb * 64 + ((g ^ (rb & 7)) * 8);
                fBh[f] = *(const bf16x8*)&sBh[ab];
                fBl[f] = *(const bf16x8*)&sBl[ab];
            }
            #pragma unroll
            for (int fi = 0; fi < 2; ++fi)
                #pragma unroll
                for (int fj = 0; fj < 4; ++fj) {
                    acc[fi][fj] = __builtin_amdgcn_mfma_f32_16x16x32_bf16(
                        fAh[fi], fBh[fj], acc[fi][fj], 0, 0, 0);
                    acc[fi][fj] = __builtin_amdgcn_mfma_f32_16x16x32_bf16(
                        fAh[fi], fBl[fj], acc[fi][fj], 0, 0, 0);
                    acc[fi][fj] = __builtin_amdgcn_mfma_f32_16x16x32_bf16(
                        fAl[fi], fBh[fj], acc[fi][fj], 0, 0, 0);
                }
        }
        __syncthreads();
    }

    #pragma unroll
    for (int fi = 0; fi < 2; ++fi)
        #pragma unroll
        for (int fj = 0; fj < 4; ++fj) {
            int col = j0 + fj * 16 + r15;
            if (col >= j_valid) continue;
            #pragma unroll
            for (int r = 0; r < 4; ++r) {
                int row = i0 + wr + fi * 16 + q * 4 + r;
                if (row >= i_valid) continue;
                float v = acc[fi][fj][r];
                if (BIASM == 1) v += bias[row];
                if (BIASM == 2) v += bias[col];
                if (RELU) v = fmaxf(v, 0.f);
                long off = TSTORE ? ((long)col * ldc + row)
                                  : ((long)row * ldc + col);
                if (OUTF32) {
                    Cf[off] = v;
                } else {
                    unsigned short h = bf16_rne(v);
                    Ch[off] = h;
                    Cl[off] = bf16_rne(v - bf16_f(h));
                }
            }
        }
}

// ---------------------------------------------------------------------------
// Prep (fused): all 4 t per thread (one evc read); zeroes sumsq + counter.
// ---------------------------------------------------------------------------
__global__ __launch_bounds__(256)
void prep_filter_A(const float* __restrict__ V, const float* __restrict__ sig,
                   unsigned short* __restrict__ Ah, float* __restrict__ zs,
                   unsigned* __restrict__ ctr)
{
    if (blockIdx.x < 32)
        zs[blockIdx.x * 256 + threadIdx.x] = 0.f;
    if (blockIdx.x == 32 && threadIdx.x == 0)
        *ctr = 0u;
    long idx = ((long)blockIdx.x * 256 + threadIdx.x) * 4;
    int k = (int)(idx & (NN - 1));
    float4 v = *(const float4*)(V + idx);
    float vv[4] = {v.x, v.y, v.z, v.w};
    float4 srow[4];
    #pragma unroll
    for (int i = 0; i < 4; ++i)
        srow[i] = *(const float4*)(sig + (k + i) * 4);
    #pragma unroll
    for (int t = 0; t < 4; ++t) {
        float sq[4] = {((const float*)&srow[0])[t], ((const float*)&srow[1])[t],
                       ((const float*)&srow[2])[t], ((const float*)&srow[3])[t]};
        ushort4 hi, lo;
        unsigned short h;
        float a;
        a = vv[0] * sqrtf(sq[0]); h = bf16_rne(a); hi.x = h; lo.x = bf16_rne(a - bf16_f(h));
        a = vv[1] * sqrtf(sq[1]); h = bf16_rne(a); hi.y = h; lo.y = bf16_rne(a - bf16_f(h));
        a = vv[2] * sqrtf(sq[2]); h = bf16_rne(a); hi.z = h; lo.z = bf16_rne(a - bf16_f(h));
        a = vv[3] * sqrtf(sq[3]); h = bf16_rne(a); hi.w = h; lo.w = bf16_rne(a - bf16_f(h));
        *(ushort4*)(Ah + (long)t * 2 * NPW + idx) = hi;
        *(ushort4*)(Ah + (long)t * 2 * NPW + NPW + idx) = lo;
    }
}

// Fallback prep: single t; zeroes counter every launch, sumsq only when zs set.
__global__ __launch_bounds__(256)
void prep_filter_A1(const float* __restrict__ V, const float* __restrict__ sig, int t,
                    unsigned short* __restrict__ Ah, unsigned short* __restrict__ Al,
                    float* __restrict__ zs, unsigned* __restrict__ ctr)
{
    if (zs && blockIdx.x < 32)
        zs[blockIdx.x * 256 + threadIdx.x] = 0.f;
    if (blockIdx.x == 32 && threadIdx.x == 0)
        *ctr = 0u;
    long idx = ((long)blockIdx.x * 256 + threadIdx.x) * 4;
    int k = (int)(idx & (NN - 1));
    float4 v = *(const float4*)(V + idx);
    float a[4];
    a[0] = v.x * sqrtf(sig[(k + 0) * 4 + t]);
    a[1] = v.y * sqrtf(sig[(k + 1) * 4 + t]);
    a[2] = v.z * sqrtf(sig[(k + 2) * 4 + t]);
    a[3] = v.w * sqrtf(sig[(k + 3) * 4 + t]);
    ushort4 hi, lo;
    unsigned short h;
    h = bf16_rne(a[0]); hi.x = h; lo.x = bf16_rne(a[0] - bf16_f(h));
    h = bf16_rne(a[1]); hi.y = h; lo.y = bf16_rne(a[1] - bf16_f(h));
    h = bf16_rne(a[2]); hi.z = h; lo.z = bf16_rne(a[2] - bf16_f(h));
    h = bf16_rne(a[3]); hi.w = h; lo.w = bf16_rne(a[3] - bf16_f(h));
    *(ushort4*)(Ah + idx) = hi;
    *(ushort4*)(Al + idx) = lo;
}

__global__ __launch_bounds__(256)
void split_kernel(const float* __restrict__ src,
                  unsigned short* __restrict__ oh, unsigned short* __restrict__ ol,
                  const float* __restrict__ bg, float* __restrict__ bgp)
{
    if (blockIdx.x == 0 && bgp) {
        #pragma unroll
        for (int p = 0; p < 4; ++p) {
            int i = p * 256 + threadIdx.x;
            int t = i >> 8, n = i & 255;
            bgp[i] = (n < 192) ? bg[t * 192 + n] : 0.f;
        }
    }
    long idx = ((long)blockIdx.x * 256 + threadIdx.x) * 4;
    float4 v = *(const float4*)(src + idx);
    float a[4] = {v.x, v.y, v.z, v.w};
    ushort4 hi, lo;
    unsigned short h;
    h = bf16_rne(a[0]); hi.x = h; lo.x = bf16_rne(a[0] - bf16_f(h));
    h = bf16_rne(a[1]); hi.y = h; lo.y = bf16_rne(a[1] - bf16_f(h));
    h = bf16_rne(a[2]); hi.z = h; lo.z = bf16_rne(a[2] - bf16_f(h));
    h = bf16_rne(a[3]); hi.w = h; lo.w = bf16_rne(a[3] - bf16_f(h));
    *(ushort4*)(oh + idx) = hi;
    *(ushort4*)(ol + idx) = lo;
}

__global__ __launch_bounds__(256)
void transpose_split(const float* __restrict__ src, int src_ld, int n_rows, int n_valid,
                     int kcols, unsigned short* __restrict__ oh, unsigned short* __restrict__ ol,
                     long sbs, long sbd)
{
    long idx = (long)blockIdx.x * 256 + threadIdx.x;
    if (idx >= (long)n_rows * kcols) return;
    int n = (int)(idx / kcols), k = (int)(idx % kcols);
    float v = (n < n_valid) ? src[(long)blockIdx.y * sbs + (long)k * src_ld + n] : 0.f;
    unsigned short h = bf16_rne(v);
    long o = (long)blockIdx.y * sbd + idx;
    oh[o] = h;
    ol[o] = bf16_rne(v - bf16_f(h));
}

// ---------------------------------------------------------------------------
extern "C" void kernel_launch(void* const* d_in, const int* in_sizes, int n_in,
                              void* d_out, int out_size, void* d_ws, size_t ws_size,
                              hipStream_t stream)
{
    const float* x   = (const float*)d_in[0];
    const float* evc = (const float*)d_in[1];
    const float* sig = (const float*)d_in[2];
    const float* Wg  = (const float*)d_in[3];
    const float* bg  = (const float*)d_in[4];
    const float* Wf  = (const float*)d_in[5];
    const float* bf  = (const float*)d_in[6];
    float* out = (float*)d_out;

    char* w = (char*)d_ws;
    float* F = (float*)w;                                       // [4][N][N] fp32
    char* R = w + 67108864L;
    unsigned short* A1 = (unsigned short*)R;                    // fallback pair
    unsigned short* xh   = (unsigned short*)R;
    unsigned short* xl   = xh + (long)NN * 768;
    unsigned short* WgTh = (unsigned short*)(R + 6291456L);
    unsigned short* WgTl = WgTh + 4L * 256 * 768;
    unsigned short* PTh  = (unsigned short*)(R + 9437184L);
    unsigned short* PTl  = PTh + 4L * 192 * NN;
    unsigned short* HTh  = (unsigned short*)R;
    unsigned short* HTl  = HTh + 4L * 192 * NN;
    unsigned short* combh = (unsigned short*)(R + 9437184L);
    unsigned short* combl = combh + (long)NN * 768;
    unsigned short* WfTh = (unsigned short*)w;                  // overlays dead F
    unsigned short* WfTl = WfTh + 768L * 768;

    const bool fused = ws_size >= 134254592UL;
    float* rowss = (float*)(fused ? (w + 134217728L) : (w + 83886080L));
    float* bgp   = rowss + 4 * NN;
    unsigned* ctr = (unsigned*)bgp;   // bgp slot is dead until split_kernel

    if (fused) {
        unsigned short* A4 = (unsigned short*)R;   // [4][hi|lo][N*N]
        prep_filter_A<<<4096, 256, 0, stream>>>(evc, sig, A4, rowss, ctr);
        filter_persist<<<512, 256, 0, stream>>>(
            A4, A4 + NPW, F, rowss, 2 * NPW, 544, ctr);
    } else {
        for (int t = 0; t < 4; ++t) {
            prep_filter_A1<<<4096, 256, 0, stream>>>(
                evc, sig, t, A1, A1 + NPW, t == 0 ? rowss : nullptr, ctr);
            filter_persist<<<136, 256, 0, stream>>>(
                A1, A1 + NPW, F + t * NPW, rowss + t * NN, 0L, 136, ctr);
        }
    }

    split_kernel<<<1536, 256, 0, stream>>>(x, xh, xl, bg, bgp);
    transpose_split<<<dim3(768, 4), 256, 0, stream>>>(
        Wg, 192, 256, 192, 768, WgTh, WgTl, 768L * 192, 256L * 768);

    // st1: PT[t] = NT(WgT_pad[t], x), K=768
    nt_gemm<0, false, false, false, false><<<dim3(32, 2, 4), 256, 0, stream>>>(
        WgTh, WgTl, xh, xl, nullptr, PTh, PTl, nullptr, nullptr, nullptr,
        768, 256, NN, 192, NN, NN, 256L * 768, 0L, 192L * NN, 0);

    // st4: HT[t] = relu(NT(PT[t], G[t]) + bg[t]); G staged from F fp32 (B side)
    nt_gemm<1, true, false, true, false><<<dim3(32, 2, 4), 256, 0, stream>>>(
        PTh, PTl, nullptr, nullptr, F, HTh, HTl, nullptr, bgp, rowss,
        NN, 192, NN, 192, NN, NN, 192L * NN, NPW, 192L * NN, 256);

    // st5 (swapped): combT-tiles = NT(HT, G), stored transposed.
    nt_gemm<0, false, false, true, true><<<dim3(32, 2, 4), 256, 0, stream>>>(
        HTh, HTl, nullptr, nullptr, F, combh, combl, nullptr, nullptr, rowss,
        NN, 192, NN, 192, NN, 768, 192L * NN, NPW, 192L, 0);

    // st6: out = relu(NT(comb, WfT) + bf)
    transpose_split<<<dim3(2304, 1), 256, 0, stream>>>(
        Wf, 768, 768, 768, 768, WfTh, WfTl, 0L, 0L);
    nt_gemm<2, true, true, false, false><<<dim3(12, 16, 1), 256, 0, stream>>>(
        combh, combl, WfTh, WfTl, nullptr, nullptr, nullptr, out, bf, nullptr,
        768, NN, 768, NN, 768, 768, 0L, 0L, 0L, 0);
}

// Round 13
// 416.607 us; speedup vs baseline: 1.0054x; 1.0054x over previous
//
#include <hip/hip_runtime.h>

// WaveGC wavelet conv. Round 13:
//  - filter reverted to R8's best-measured config (one-shot triangular grid
//    272x1x4, 128x64 tile, 4 waves, 48 KB LDS, 3 blocks/CU) + R11's diag-skip
//    (B tile == A tile on diagonal pairs). R12's 128x128 (2 blocks/CU) and
//    R11's persistent loop both measured worse than the plain R8 grid.
//  - st4/st5 (K=2048, previously 256 blocks = 1 block/CU) now split-K=2:
//    512 blocks each, fp32 atomicAdd partials (exactly 2 adds from 0 ->
//    deterministic), bias/relu/split moved to epilogue kernels.
//
//  filter: F_t = A_t A_t^T (fp32) + fused row/col sumsq, triangular+mirror
//  st1   : PT  = NT(WgT_pad, x)
//  st4   : HTf32 += NT_k-half(PT, G)   ; ep4: HT = split(relu(HTf32+bg))
//  st5   : combf32 += NT_k-half(HT, G)^T ; ep5: comb = split(combf32)
//  st6   : out = relu(NT(comb, WfT) + bf)
//
// ws (fused): F fp32 [4][N][N] @0 (67.1M) | R=67.1M region:
//   A4 (67.1M, filter phase) then overlays:
//   xh/xl @R+0 (6.3M) | WgT @R+6.29M (3.1M) | PT @R+9.44M (6.3M)
//   HTf32 @R+15.73M (6.3M) | combf32 @R+22.02M (6.3M)
//   HT bf16 @R+0 (over x) | comb bf16 @R+9.44M (over PT) | WfT @w (over F)
//   tail @134.2M: rowss | bgp
// ws (fallback, 84M): old non-split path.

#define NN 2048
#define NPW 4194304L   // N*N

typedef short bf16x8 __attribute__((ext_vector_type(8)));
typedef float f32x4  __attribute__((ext_vector_type(4)));

__device__ inline unsigned short bf16_rne(float f) {
    unsigned int u = __float_as_uint(f);
    u += 0x7fffu + ((u >> 16) & 1u);
    return (unsigned short)(u >> 16);
}
__device__ inline float bf16_f(unsigned short h) {
    return __uint_as_float((unsigned)h << 16);
}

__device__ inline void load_lds16(const void* g, void* l) {
    __builtin_amdgcn_global_load_lds(
        (const __attribute__((address_space(1))) unsigned int*)(unsigned long)g,
        (__attribute__((address_space(3))) unsigned int*)(unsigned long)l,
        16, 0, 0);
}

// masked+scaled+split 8-element chunk -> packed hi/lo uint4
__device__ inline void gmask_chunk(const float* src, float iv,
                                   uint4* hi, uint4* lo)
{
    float4 v0 = *(const float4*)src;
    float4 v1 = *(const float4*)(src + 4);
    float a[8] = {v0.x, v0.y, v0.z, v0.w, v1.x, v1.y, v1.z, v1.w};
    unsigned int hw[4], lw[4];
    #pragma unroll
    for (int d = 0; d < 4; ++d) {
        unsigned int hword = 0, lword = 0;
        #pragma unroll
        for (int e = 0; e < 2; ++e) {
            float g = a[d * 2 + e] * iv;
            g = (fabsf(g) > 1e-4f) ? g : 0.f;
            unsigned short h = bf16_rne(g);
            unsigned short l = bf16_rne(g - bf16_f(h));
            hword |= (unsigned int)h << (16 * e);
            lword |= (unsigned int)l << (16 * e);
        }
        hw[d] = hword; lw[d] = lword;
    }
    *hi = *(uint4*)hw; *lo = *(uint4*)lw;
}

// ---------------------------------------------------------------------------
// Filter: F = A A^T fp32 + fused row-sumsq. 128x64 tile, BK=64, 4 waves.
// TRI: triangular pair grid (blockIdx.x in [0,272), z = t), mirror writes +
// mirror col-sumsq; diagonal pairs ((jt>>1)==it) skip B staging (B in A tile).
// ---------------------------------------------------------------------------
template<bool TRI>
__global__ __launch_bounds__(256, 3)
void filter_tri(const unsigned short* __restrict__ Ah,
                const unsigned short* __restrict__ Al,
                float* __restrict__ F, float* __restrict__ sumsq, long sA)
{
    __shared__ unsigned short sAh[128 * 64];
    __shared__ unsigned short sAl[128 * 64];
    __shared__ unsigned short sBh[64 * 64];
    __shared__ unsigned short sBl[64 * 64];

    int z = blockIdx.z;
    Ah += z * sA; Al += z * sA;
    F  += (long)z * (TRI ? NPW : 0L);
    sumsq += z * (TRI ? NN : 0);
    const int K = NN, N = NN;

    int it, jt;
    if (TRI) {
        int rem = blockIdx.x, span = 32; it = 0;
        while (rem >= span) { rem -= span; ++it; span -= 2; }
        jt = 2 * it + rem;
    } else { it = blockIdx.y; jt = blockIdx.x; }
    int i0 = it * 128, j0 = jt * 64;
    bool diag = TRI && ((jt >> 1) == it);
    int boff = diag ? (jt & 1) * 64 : 0;

    int tid = threadIdx.x;
    int lane = tid & 63, w = tid >> 6;
    int wbase = w * 64;
    int wr = w * 32;
    int q = lane >> 4, r15 = lane & 15;

    f32x4 acc[2][4];
    #pragma unroll
    for (int i = 0; i < 2; ++i)
        #pragma unroll
        for (int j = 0; j < 4; ++j)
            acc[i][j] = (f32x4){0.f, 0.f, 0.f, 0.f};

    for (int k0 = 0; k0 < K; k0 += 64) {
        #pragma unroll
        for (int p = 0; p < 4; ++p) {
            int c = p * 256 + wbase + lane;
            int row = c >> 3;
            int gsw = (c & 7) ^ (row & 7);
            long off = (long)(i0 + row) * K + k0 + gsw * 8;
            int ldst = (p * 256 + wbase) * 8;
            load_lds16(Ah + off, &sAh[ldst]);
            load_lds16(Al + off, &sAl[ldst]);
        }
        if (!diag) {
            #pragma unroll
            for (int p = 0; p < 2; ++p) {
                int c = p * 256 + wbase + lane;
                int row = c >> 3;
                int gsw = (c & 7) ^ (row & 7);
                long off = (long)(j0 + row) * K + k0 + gsw * 8;
                int ldst = (p * 256 + wbase) * 8;
                load_lds16(Ah + off, &sBh[ldst]);   // B side == A array
                load_lds16(Al + off, &sBl[ldst]);
            }
        }
        __syncthreads();

        const unsigned short* bh = diag ? sAh : sBh;
        const unsigned short* bl = diag ? sAl : sBl;

        #pragma unroll
        for (int s = 0; s < 2; ++s) {
            int g = s * 4 + q;
            bf16x8 fAh[2], fAl[2], fBh[4], fBl[4];
            #pragma unroll
            for (int f = 0; f < 2; ++f) {
                int ra = wr + f * 16 + r15;
                int aa = ra * 64 + ((g ^ (ra & 7)) * 8);
                fAh[f] = *(const bf16x8*)&sAh[aa];
                fAl[f] = *(const bf16x8*)&sAl[aa];
            }
            #pragma unroll
            for (int f = 0; f < 4; ++f) {
                int rb = boff + f * 16 + r15;
                int ab = rb * 64 + ((g ^ (rb & 7)) * 8);
                fBh[f] = *(const bf16x8*)&bh[ab];
                fBl[f] = *(const bf16x8*)&bl[ab];
            }
            #pragma unroll
            for (int fi = 0; fi < 2; ++fi)
                #pragma unroll
                for (int fj = 0; fj < 4; ++fj) {
                    acc[fi][fj] = __builtin_amdgcn_mfma_f32_16x16x32_bf16(
                        fAh[fi], fBh[fj], acc[fi][fj], 0, 0, 0);
                    acc[fi][fj] = __builtin_amdgcn_mfma_f32_16x16x32_bf16(
                        fAh[fi], fBl[fj], acc[fi][fj], 0, 0, 0);
                    acc[fi][fj] = __builtin_amdgcn_mfma_f32_16x16x32_bf16(
                        fAl[fi], fBh[fj], acc[fi][fj], 0, 0, 0);
                }
        }
        __syncthreads();
    }

    // row-sumsq (direct contribution)
    #pragma unroll
    for (int fi = 0; fi < 2; ++fi)
        #pragma unroll
        for (int r = 0; r < 4; ++r) {
            float s = 0.f;
            #pragma unroll
            for (int fj = 0; fj < 4; ++fj) {
                float v = acc[fi][fj][r];
                s += v * v;
            }
            s += __shfl_xor(s, 1); s += __shfl_xor(s, 2);
            s += __shfl_xor(s, 4); s += __shfl_xor(s, 8);
            if (r15 == 0)
                atomicAdd(&sumsq[i0 + wr + fi * 16 + q * 4 + r], s);
        }

    bool mirror = TRI && (jt >= 2 * it + 2);
    if (mirror) {
        #pragma unroll
        for (int fj = 0; fj < 4; ++fj) {
            float s = 0.f;
            #pragma unroll
            for (int fi = 0; fi < 2; ++fi)
                #pragma unroll
                for (int r = 0; r < 4; ++r) {
                    float v = acc[fi][fj][r];
                    s += v * v;
                }
            s += __shfl_xor(s, 16); s += __shfl_xor(s, 32);
            if (lane < 16)
                atomicAdd(&sumsq[j0 + fj * 16 + lane], s);
        }
    }

    #pragma unroll
    for (int fi = 0; fi < 2; ++fi)
        #pragma unroll
        for (int fj = 0; fj < 4; ++fj) {
            int col = j0 + fj * 16 + r15;
            #pragma unroll
            for (int r = 0; r < 4; ++r) {
                int row = i0 + wr + fi * 16 + q * 4 + r;
                float v = acc[fi][fj][r];
                F[(long)row * N + col] = v;
                if (mirror) F[(long)col * N + row] = v;
            }
        }
}

// ---------------------------------------------------------------------------
// Generic NT GEMM. A: DMA staged. B: DMA, or GB: gmask-staged from fp32 F.
// BIASM: 0/1/2. TSTORE: transposed C. KSPLIT: z = zt*KSPLIT+ks, block sums
// k in [ks*K/KSPLIT, (ks+1)*K/KSPLIT). PARTIAL: atomicAdd fp32 into Cf
// (no bias/relu; requires OUTF32).
// ---------------------------------------------------------------------------
template<int BIASM, bool RELU, bool OUTF32, bool GB, bool TSTORE, int KSPLIT, bool PARTIAL>
__global__ __launch_bounds__(256, 3)
void nt_gemm(const unsigned short* __restrict__ Ah, const unsigned short* __restrict__ Al,
             const unsigned short* __restrict__ Bh, const unsigned short* __restrict__ Bl,
             const float* __restrict__ Bf,
             unsigned short* __restrict__ Ch, unsigned short* __restrict__ Cl,
             float* __restrict__ Cf,
             const float* __restrict__ bias, const float* __restrict__ rowss,
             int K, int a_rows, int b_rows, int i_valid, int j_valid, int ldc,
             long sA, long sB, long sC, int sBias)
{
    __shared__ unsigned short sAh[128 * 64];
    __shared__ unsigned short sAl[128 * 64];
    __shared__ unsigned short sBh[64 * 64];
    __shared__ unsigned short sBl[64 * 64];

    int z = blockIdx.z;
    int zt = z / KSPLIT, ks = z % KSPLIT;
    Ah += zt * sA; Al += zt * sA;
    if (GB) Bf += zt * sB; else { Bh += zt * sB; Bl += zt * sB; }
    if (OUTF32) Cf += zt * sC; else { Ch += zt * sC; Cl += zt * sC; }
    if (BIASM)  bias += (long)zt * sBias;
    if (GB) rowss += zt * NN;

    int kb = ks * (K / KSPLIT);
    int ke = kb + K / KSPLIT;

    int i0 = blockIdx.y * 128, j0 = blockIdx.x * 64;
    int tid = threadIdx.x;
    int lane = tid & 63, w = tid >> 6;
    int wbase = w * 64;
    int wr = w * 32;
    int q = lane >> 4, r15 = lane & 15;

    f32x4 acc[2][4];
    #pragma unroll
    for (int i = 0; i < 2; ++i)
        #pragma unroll
        for (int j = 0; j < 4; ++j)
            acc[i][j] = (f32x4){0.f, 0.f, 0.f, 0.f};

    for (int k0 = kb; k0 < ke; k0 += 64) {
        #pragma unroll
        for (int p = 0; p < 4; ++p) {
            int c = p * 256 + wbase + lane;
            int row = c >> 3;
            int gsw = (c & 7) ^ (row & 7);
            int ra = min(i0 + row, a_rows - 1);
            long off = (long)ra * K + k0 + gsw * 8;
            int ldst = (p * 256 + wbase) * 8;
            load_lds16(Ah + off, &sAh[ldst]);
            load_lds16(Al + off, &sAl[ldst]);
        }
        if (GB) {
            #pragma unroll
            for (int p = 0; p < 2; ++p) {
                int c = p * 256 + tid;
                int row = c >> 3, g = c & 7;
                int rb = min(j0 + row, b_rows - 1);
                float iv = 1.f / fmaxf(sqrtf(rowss[rb]), 1e-12f);
                uint4 hi, lo;
                gmask_chunk(Bf + (long)rb * K + k0 + g * 8, iv, &hi, &lo);
                int slot = row * 64 + ((g ^ (row & 7)) * 8);
                *(uint4*)&sBh[slot] = hi;
                *(uint4*)&sBl[slot] = lo;
            }
        } else {
            #pragma unroll
            for (int p = 0; p < 2; ++p) {
                int c = p * 256 + wbase + lane;
                int row = c >> 3;
                int gsw = (c & 7) ^ (row & 7);
                int rb = min(j0 + row, b_rows - 1);
                long off = (long)rb * K + k0 + gsw * 8;
                int ldst = (p * 256 + wbase) * 8;
                load_lds16(Bh + off, &sBh[ldst]);
                load_lds16(Bl + off, &sBl[ldst]);
            }
        }
        __syncthreads();

        #pragma unroll
        for (int s = 0; s < 2; ++s) {
            int g = s * 4 + q;
            bf16x8 fAh[2], fAl[2], fBh[4], fBl[4];
            #pragma unroll
            for (int f = 0; f < 2; ++f) {
                int ra = wr + f * 16 + r15;
                int aa = ra * 64 + ((g ^ (ra & 7)) * 8);
                fAh[f] = *(const bf16x8*)&sAh[aa];
                fAl[f] = *(const bf16x8*)&sAl[aa];
            }
            #pragma unroll
            for (int f = 0; f < 4; ++f) {
                int rb = f * 16 + r15;
                int ab = rb * 64 + ((g ^ (rb & 7)) * 8);
                fBh[f] = *(const bf16x8*)&sBh[ab];
                fBl[f] = *(const bf16x8*)&sBl[ab];
            }
            #pragma unroll
            for (int fi = 0; fi < 2; ++fi)
                #pragma unroll
                for (int fj = 0; fj < 4; ++fj) {
                    acc[fi][fj] = __builtin_amdgcn_mfma_f32_16x16x32_bf16(
                        fAh[fi], fBh[fj], acc[fi][fj], 0, 0, 0);
                    acc[fi][fj] = __builtin_amdgcn_mfma_f32_16x16x32_bf16(
                        fAh[fi], fBl[fj], acc[fi][fj], 0, 0, 0);
                    acc[fi][fj] = __builtin_amdgcn_mfma_f32_16x16x32_bf16(
                        fAl[fi], fBh[fj], acc[fi][fj], 0, 0, 0);
                }
        }
        __syncthreads();
    }

    #pragma unroll
    for (int fi = 0; fi < 2; ++fi)
        #pragma unroll
        for (int fj = 0; fj < 4; ++fj) {
            int col = j0 + fj * 16 + r15;
            if (col >= j_valid) continue;
            #pragma unroll
            for (int r = 0; r < 4; ++r) {
                int row = i0 + wr + fi * 16 + q * 4 + r;
                if (row >= i_valid) continue;
                float v = acc[fi][fj][r];
                if (BIASM == 1) v += bias[row];
                if (BIASM == 2) v += bias[col];
                if (RELU) v = fmaxf(v, 0.f);
                long off = TSTORE ? ((long)col * ldc + row)
                                  : ((long)row * ldc + col);
                if (PARTIAL) {
                    atomicAdd(&Cf[off], v);
                } else if (OUTF32) {
                    Cf[off] = v;
                } else {
                    unsigned short h = bf16_rne(v);
                    Ch[off] = h;
                    Cl[off] = bf16_rne(v - bf16_f(h));
                }
            }
        }
}

// ---------------------------------------------------------------------------
// Epilogues for split-K partials.
// ep_st4: HT = split(relu(HTf32 + bg[row])); layout [4][192][2048], grid (384,4)
// ep_st5: comb = split(combf32); 2048*768 elems, grid 1536
// ---------------------------------------------------------------------------
__global__ __launch_bounds__(256)
void ep_st4(const float* __restrict__ src, const float* __restrict__ bgp,
            unsigned short* __restrict__ oh, unsigned short* __restrict__ ol)
{
    int t = blockIdx.y;
    long base = (long)t * 393216;   // 192*2048
    long idx = ((long)blockIdx.x * 256 + threadIdx.x) * 4;
    int r = (int)(idx >> 11);
    float b = bgp[t * 256 + r];
    float4 v = *(const float4*)(src + base + idx);
    float a[4] = {v.x + b, v.y + b, v.z + b, v.w + b};
    ushort4 hi, lo;
    unsigned short h;
    float g;
    g = fmaxf(a[0], 0.f); h = bf16_rne(g); hi.x = h; lo.x = bf16_rne(g - bf16_f(h));
    g = fmaxf(a[1], 0.f); h = bf16_rne(g); hi.y = h; lo.y = bf16_rne(g - bf16_f(h));
    g = fmaxf(a[2], 0.f); h = bf16_rne(g); hi.z = h; lo.z = bf16_rne(g - bf16_f(h));
    g = fmaxf(a[3], 0.f); h = bf16_rne(g); hi.w = h; lo.w = bf16_rne(g - bf16_f(h));
    *(ushort4*)(oh + base + idx) = hi;
    *(ushort4*)(ol + base + idx) = lo;
}

__global__ __launch_bounds__(256)
void ep_st5(const float* __restrict__ src,
            unsigned short* __restrict__ oh, unsigned short* __restrict__ ol)
{
    long idx = ((long)blockIdx.x * 256 + threadIdx.x) * 4;
    float4 v = *(const float4*)(src + idx);
    float a[4] = {v.x, v.y, v.z, v.w};
    ushort4 hi, lo;
    unsigned short h;
    h = bf16_rne(a[0]); hi.x = h; lo.x = bf16_rne(a[0] - bf16_f(h));
    h = bf16_rne(a[1]); hi.y = h; lo.y = bf16_rne(a[1] - bf16_f(h));
    h = bf16_rne(a[2]); hi.z = h; lo.z = bf16_rne(a[2] - bf16_f(h));
    h = bf16_rne(a[3]); hi.w = h; lo.w = bf16_rne(a[3] - bf16_f(h));
    *(ushort4*)(oh + idx) = hi;
    *(ushort4*)(ol + idx) = lo;
}

__global__ __launch_bounds__(256)
void zero4(float* __restrict__ p)
{
    long i = ((long)blockIdx.x * 256 + threadIdx.x) * 4;
    *(float4*)(p + i) = make_float4(0.f, 0.f, 0.f, 0.f);
}

// ---------------------------------------------------------------------------
// Prep (fused): all 4 t per thread (one evc read); zeroes sumsq.
// ---------------------------------------------------------------------------
__global__ __launch_bounds__(256)
void prep_filter_A(const float* __restrict__ V, const float* __restrict__ sig,
                   unsigned short* __restrict__ Ah, float* __restrict__ zs)
{
    if (blockIdx.x < 32)
        zs[blockIdx.x * 256 + threadIdx.x] = 0.f;
    long idx = ((long)blockIdx.x * 256 + threadIdx.x) * 4;
    int k = (int)(idx & (NN - 1));
    float4 v = *(const float4*)(V + idx);
    float vv[4] = {v.x, v.y, v.z, v.w};
    float4 srow[4];
    #pragma unroll
    for (int i = 0; i < 4; ++i)
        srow[i] = *(const float4*)(sig + (k + i) * 4);
    #pragma unroll
    for (int t = 0; t < 4; ++t) {
        float sq[4] = {((const float*)&srow[0])[t], ((const float*)&srow[1])[t],
                       ((const float*)&srow[2])[t], ((const float*)&srow[3])[t]};
        ushort4 hi, lo;
        unsigned short h;
        float a;
        a = vv[0] * sqrtf(sq[0]); h = bf16_rne(a); hi.x = h; lo.x = bf16_rne(a - bf16_f(h));
        a = vv[1] * sqrtf(sq[1]); h = bf16_rne(a); hi.y = h; lo.y = bf16_rne(a - bf16_f(h));
        a = vv[2] * sqrtf(sq[2]); h = bf16_rne(a); hi.z = h; lo.z = bf16_rne(a - bf16_f(h));
        a = vv[3] * sqrtf(sq[3]); h = bf16_rne(a); hi.w = h; lo.w = bf16_rne(a - bf16_f(h));
        *(ushort4*)(Ah + (long)t * 2 * NPW + idx) = hi;
        *(ushort4*)(Ah + (long)t * 2 * NPW + NPW + idx) = lo;
    }
}

// Fallback prep: single t.
__global__ __launch_bounds__(256)
void prep_filter_A1(const float* __restrict__ V, const float* __restrict__ sig, int t,
                    unsigned short* __restrict__ Ah, unsigned short* __restrict__ Al,
                    float* __restrict__ zs)
{
    if (zs && blockIdx.x < 32)
        zs[blockIdx.x * 256 + threadIdx.x] = 0.f;
    long idx = ((long)blockIdx.x * 256 + threadIdx.x) * 4;
    int k = (int)(idx & (NN - 1));
    float4 v = *(const float4*)(V + idx);
    float a[4];
    a[0] = v.x * sqrtf(sig[(k + 0) * 4 + t]);
    a[1] = v.y * sqrtf(sig[(k + 1) * 4 + t]);
    a[2] = v.z * sqrtf(sig[(k + 2) * 4 + t]);
    a[3] = v.w * sqrtf(sig[(k + 3) * 4 + t]);
    ushort4 hi, lo;
    unsigned short h;
    h = bf16_rne(a[0]); hi.x = h; lo.x = bf16_rne(a[0] - bf16_f(h));
    h = bf16_rne(a[1]); hi.y = h; lo.y = bf16_rne(a[1] - bf16_f(h));
    h = bf16_rne(a[2]); hi.z = h; lo.z = bf16_rne(a[2] - bf16_f(h));
    h = bf16_rne(a[3]); hi.w = h; lo.w = bf16_rne(a[3] - bf16_f(h));
    *(ushort4*)(Ah + idx) = hi;
    *(ushort4*)(Al + idx) = lo;
}

__global__ __launch_bounds__(256)
void split_kernel(const float* __restrict__ src,
                  unsigned short* __restrict__ oh, unsigned short* __restrict__ ol,
                  const float* __restrict__ bg, float* __restrict__ bgp)
{
    if (blockIdx.x == 0 && bgp) {
        #pragma unroll
        for (int p = 0; p < 4; ++p) {
            int i = p * 256 + threadIdx.x;
            int t = i >> 8, n = i & 255;
            bgp[i] = (n < 192) ? bg[t * 192 + n] : 0.f;
        }
    }
    long idx = ((long)blockIdx.x * 256 + threadIdx.x) * 4;
    float4 v = *(const float4*)(src + idx);
    float a[4] = {v.x, v.y, v.z, v.w};
    ushort4 hi, lo;
    unsigned short h;
    h = bf16_rne(a[0]); hi.x = h; lo.x = bf16_rne(a[0] - bf16_f(h));
    h = bf16_rne(a[1]); hi.y = h; lo.y = bf16_rne(a[1] - bf16_f(h));
    h = bf16_rne(a[2]); hi.z = h; lo.z = bf16_rne(a[2] - bf16_f(h));
    h = bf16_rne(a[3]); hi.w = h; lo.w = bf16_rne(a[3] - bf16_f(h));
    *(ushort4*)(oh + idx) = hi;
    *(ushort4*)(ol + idx) = lo;
}

__global__ __launch_bounds__(256)
void transpose_split(const float* __restrict__ src, int src_ld, int n_rows, int n_valid,
                     int kcols, unsigned short* __restrict__ oh, unsigned short* __restrict__ ol,
                     long sbs, long sbd)
{
    long idx = (long)blockIdx.x * 256 + threadIdx.x;
    if (idx >= (long)n_rows * kcols) return;
    int n = (int)(idx / kcols), k = (int)(idx % kcols);
    float v = (n < n_valid) ? src[(long)blockIdx.y * sbs + (long)k * src_ld + n] : 0.f;
    unsigned short h = bf16_rne(v);
    long o = (long)blockIdx.y * sbd + idx;
    oh[o] = h;
    ol[o] = bf16_rne(v - bf16_f(h));
}

// ---------------------------------------------------------------------------
extern "C" void kernel_launch(void* const* d_in, const int* in_sizes, int n_in,
                              void* d_out, int out_size, void* d_ws, size_t ws_size,
                              hipStream_t stream)
{
    const float* x   = (const float*)d_in[0];
    const float* evc = (const float*)d_in[1];
    const float* sig = (const float*)d_in[2];
    const float* Wg  = (const float*)d_in[3];
    const float* bg  = (const float*)d_in[4];
    const float* Wf  = (const float*)d_in[5];
    const float* bf  = (const float*)d_in[6];
    float* out = (float*)d_out;

    char* w = (char*)d_ws;
    float* F = (float*)w;                                       // [4][N][N] fp32
    char* R = w + 67108864L;
    unsigned short* A1 = (unsigned short*)R;                    // fallback pair
    unsigned short* xh   = (unsigned short*)R;
    unsigned short* xl   = xh + (long)NN * 768;
    unsigned short* WgTh = (unsigned short*)(R + 6291456L);
    unsigned short* WgTl = WgTh + 4L * 256 * 768;
    unsigned short* PTh  = (unsigned short*)(R + 9437184L);
    unsigned short* PTl  = PTh + 4L * 192 * NN;
    float* HTf32  = (float*)(R + 15728640L);                    // [4][192][2048]
    float* combf32 = (float*)(R + 22020096L);                   // [2048][768]
    unsigned short* HTh  = (unsigned short*)R;                  // over x after st1
    unsigned short* HTl  = HTh + 4L * 192 * NN;
    unsigned short* combh = (unsigned short*)(R + 9437184L);    // over PT after st4
    unsigned short* combl = combh + (long)NN * 768;
    unsigned short* WfTh = (unsigned short*)w;                  // overlays dead F
    unsigned short* WfTl = WfTh + 768L * 768;

    const bool fused = ws_size >= 134254592UL;
    float* rowss = (float*)(fused ? (w + 134217728L) : (w + 83886080L));
    float* bgp   = rowss + 4 * NN;

    if (fused) {
        unsigned short* A4 = (unsigned short*)R;   // [4][hi|lo][N*N]
        prep_filter_A<<<4096, 256, 0, stream>>>(evc, sig, A4, rowss);
        filter_tri<true><<<dim3(272, 1, 4), 256, 0, stream>>>(
            A4, A4 + NPW, F, rowss, 2 * NPW);
    } else {
        for (int t = 0; t < 4; ++t) {
            prep_filter_A1<<<4096, 256, 0, stream>>>(
                evc, sig, t, A1, A1 + NPW, t == 0 ? rowss : nullptr);
            filter_tri<false><<<dim3(32, 16, 1), 256, 0, stream>>>(
                A1, A1 + NPW, F + t * NPW, rowss + t * NN, 0L);
        }
    }

    split_kernel<<<1536, 256, 0, stream>>>(x, xh, xl, bg, bgp);
    transpose_split<<<dim3(768, 4), 256, 0, stream>>>(
        Wg, 192, 256, 192, 768, WgTh, WgTl, 768L * 192, 256L * 768);

    // st1: PT[t] = NT(WgT_pad[t], x), K=768, grid 256
    nt_gemm<0, false, false, false, false, 1, false><<<dim3(32, 2, 4), 256, 0, stream>>>(
        WgTh, WgTl, xh, xl, nullptr, PTh, PTl, nullptr, nullptr, nullptr,
        768, 256, NN, 192, NN, NN, 256L * 768, 0L, 192L * NN, 0);

    if (fused) {
        // zero split-K partial buffers (HTf32 + combf32, contiguous 12.6 MB)
        zero4<<<3072, 256, 0, stream>>>(HTf32);

        // st4 split-K=2: HTf32 += NT(PT, G) half-K. grid 512 blocks.
        nt_gemm<0, false, true, true, false, 2, true><<<dim3(32, 2, 8), 256, 0, stream>>>(
            PTh, PTl, nullptr, nullptr, F, nullptr, nullptr, HTf32, nullptr, rowss,
            NN, 192, NN, 192, NN, NN, 192L * NN, NPW, 192L * NN, 0);
        ep_st4<<<dim3(384, 4), 256, 0, stream>>>(HTf32, bgp, HTh, HTl);

        // st5 split-K=2: combf32 += NT(HT, G)^T half-K. grid 512 blocks.
        nt_gemm<0, false, true, true, true, 2, true><<<dim3(32, 2, 8), 256, 0, stream>>>(
            HTh, HTl, nullptr, nullptr, F, nullptr, nullptr, combf32, nullptr, rowss,
            NN, 192, NN, 192, NN, 768, 192L * NN, NPW, 192L, 0);
        ep_st5<<<1536, 256, 0, stream>>>(combf32, combh, combl);
    } else {
        // st4: HT[t] = relu(NT(PT[t], G[t]) + bg[t])
        nt_gemm<1, true, false, true, false, 1, false><<<dim3(32, 2, 4), 256, 0, stream>>>(
            PTh, PTl, nullptr, nullptr, F, HTh, HTl, nullptr, bgp, rowss,
            NN, 192, NN, 192, NN, NN, 192L * NN, NPW, 192L * NN, 256);
        // st5: combT-tiles = NT(HT, G), stored transposed
        nt_gemm<0, false, false, true, true, 1, false><<<dim3(32, 2, 4), 256, 0, stream>>>(
            HTh, HTl, nullptr, nullptr, F, combh, combl, nullptr, nullptr, rowss,
            NN, 192, NN, 192, NN, 768, 192L * NN, NPW, 192L, 0);
    }

    // st6: out = relu(NT(comb, WfT) + bf)
    transpose_split<<<dim3(2304, 1), 256, 0, stream>>>(
        Wf, 768, 768, 768, 768, WfTh, WfTl, 0L, 0L);
    nt_gemm<2, true, true, false, false, 1, false><<<dim3(12, 16, 1), 256, 0, stream>>>(
        combh, combl, WfTh, WfTl, nullptr, nullptr, nullptr, out, bf, nullptr,
        768, NN, 768, NN, 768, 768, 0L, 0L, 0L, 0);
}